// Round 7
// baseline (188.770 us; speedup 1.0000x reference)
//
#include <hip/hip_runtime.h>
#include <hip/hip_cooperative_groups.h>

namespace cg = cooperative_groups;

// x shape (8,32,256,256) float32 holding exact integers 0..255; K=3, stride 1, no pad.
#define B_   8
#define C_   32
#define H_   256
#define W_   256
#define BC_  (B_ * C_)          // 256 = one block per image
#define HO_  (H_ - 2)           // 254
#define WO_  (W_ - 2)           // 254
#define NBINS 256
#define HCOLS 16                // sub-histogram columns (LDS-atomic aliasing ~2-way = free)
#define PROWS 32                // histogram fan-in rows: 256 blocks / 32 = 8 atomics per address

// Module-owned scratch (d_ws unsafe — R1). R4 lesson: deep device-atomic fan-in is
// ~34 ns per op per address; keep fan-in depth tiny (8 here).
__device__ int g_part[PROWS * NBINS];   // 32 KB partial histograms

__global__ __launch_bounds__(1024) void zero_part_kernel() {
    const int t = threadIdx.x;
#pragma unroll
    for (int i = 0; i < (PROWS * NBINS) / 1024; ++i) g_part[i * 1024 + t] = 0;
}

// One cooperative kernel: histogram -> grid sync -> pool. One block per bc image;
// phase-2 re-reads the block's own 256 KB image from its XCD's L2 (guaranteed warm,
// unlike cross-dispatch LLC state — R6 lesson: never trade cached reads for HBM writes).
__global__ __launch_bounds__(1024) void fused_kernel(const float* __restrict__ x,
                                                     float* __restrict__ out) {
    __shared__ int tile[18 * W_];    // 18 KB: sub-hist (first 16 KB) in phase 1, key tile in phase 2
    __shared__ int key_s[NBINS];
    const int t = threadIdx.x;
    const int bc = blockIdx.x;
    const float4* ximg = (const float4*)(x + (long long)bc * H_ * W_);

    // ---- Phase 1: per-block histogram (image read #1, 8 loads in flight) ----
    int* sh = tile;                  // NBINS*HCOLS = 4096 ints
    for (int i = t; i < NBINS * HCOLS; i += 1024) sh[i] = 0;
    __syncthreads();

    const int col = t & (HCOLS - 1);
#pragma unroll
    for (int half = 0; half < 2; ++half) {
        float4 v[8];
#pragma unroll
        for (int k = 0; k < 8; ++k) v[k] = ximg[t + (half * 8 + k) * 1024];
#pragma unroll
        for (int k = 0; k < 8; ++k) {
            atomicAdd(&sh[((int)v[k].x) * HCOLS + col], 1);
            atomicAdd(&sh[((int)v[k].y) * HCOLS + col], 1);
            atomicAdd(&sh[((int)v[k].z) * HCOLS + col], 1);
            atomicAdd(&sh[((int)v[k].w) * HCOLS + col], 1);
        }
    }
    __syncthreads();

    if (t < NBINS) {
        int s0 = 0;
#pragma unroll
        for (int c = 0; c < HCOLS; ++c)               // rotated: bank 2-way = free
            s0 += sh[t * HCOLS + ((c + t) & (HCOLS - 1))];
        atomicAdd(&g_part[(bc & (PROWS - 1)) * NBINS + t], s0);  // depth-8 fan-in
    }

    cg::this_grid().sync();

    // ---- Global histogram -> fused key table (count<<8 | value) ----
    if (t < NBINS) {
        int g = 0;
#pragma unroll
        for (int r = 0; r < PROWS; ++r) g += g_part[r * NBINS + t];  // coalesced, L2
        key_s[t] = (g << 8) | t;
    }
    __syncthreads();

    // ---- Phase 2: pool in 16-row strips (image read #2 from own-XCD L2) ----
    const int cidx = t & 255;        // output column
    const int rg   = t >> 8;         // 0..3: 4-row group within strip
    for (int s = 0; s < 16; ++s) {
        const int r0 = s * 16;
        const int rows_out = (s == 15) ? 14 : 16;
        const int rows_in  = rows_out + 2;           // 18 (last strip 16)

        // Convert rows [r0, r0+rows_in) to keys: ONE lookup per element, stride-1 tile.
        const float4* xrow = (const float4*)(x + ((long long)bc * H_ + r0) * W_);
        const int nf4 = rows_in * (W_ / 4);          // 1152 / 1024
        for (int idx = t; idx < nf4; idx += 1024) {
            float4 v = xrow[idx];
            int4 k;
            k.x = key_s[(int)v.x];
            k.y = key_s[(int)v.y];
            k.z = key_s[(int)v.z];
            k.w = key_s[(int)v.w];
            ((int4*)tile)[idx] = k;
        }
        __syncthreads();

        // Each thread: up to 4 output rows, 3-register rotation, 3 new LDS reads/row.
        // Argmin on (key & ~255) strict '<' == exact positional first-min (row-major di,dj).
        const int rbase = rg * 4;
        const int rcnt = (rows_out - rbase < 4) ? (rows_out - rbase) : 4;  // strip 15 rg3: 2
        if (cidx < WO_ && rcnt > 0) {
            const int* tp = tile + cidx;
            int a0 = tp[rbase * W_],       a1 = tp[rbase * W_ + 1],       a2 = tp[rbase * W_ + 2];
            int b0 = tp[(rbase + 1) * W_], b1 = tp[(rbase + 1) * W_ + 1], b2 = tp[(rbase + 1) * W_ + 2];
            float* orow = out + ((long long)bc * HO_ + r0 + rbase) * WO_ + cidx;
            for (int r = 0; r < rcnt; ++r) {
                const int cb = (rbase + 2 + r) * W_;
                const int c0 = tp[cb], c1 = tp[cb + 1], c2 = tp[cb + 2];
                int best = a0, bm = a0 & ~255;
#define CAND(kk) { const int m = (kk) & ~255; if (m < bm) { bm = m; best = (kk); } }
                CAND(a1) CAND(a2) CAND(b0) CAND(b1) CAND(b2) CAND(c0) CAND(c1) CAND(c2)
#undef CAND
                orow[(long long)r * WO_] = (float)(best & 255);
                a0 = b0; a1 = b1; a2 = b2;
                b0 = c0; b1 = c1; b2 = c2;
            }
        }
        __syncthreads();   // tile reused next strip
    }
}

extern "C" void kernel_launch(void* const* d_in, const int* in_sizes, int n_in,
                              void* d_out, int out_size, void* d_ws, size_t ws_size,
                              hipStream_t stream) {
    const float* x = (const float*)d_in[0];
    float* out = (float*)d_out;
    (void)d_ws; (void)ws_size;

    zero_part_kernel<<<1, 1024, 0, stream>>>();

    void* args[] = { (void*)&x, (void*)&out };
    hipLaunchCooperativeKernel((const void*)fused_kernel, dim3(BC_), dim3(1024),
                               args, 0, stream);
}

// Round 9
// 152.049 us; speedup vs baseline: 1.2415x; 1.2415x over previous
//
#include <hip/hip_runtime.h>

// x shape (8,32,256,256) float32 holding exact integers 0..255; K=3, stride 1, no pad.
#define B_   8
#define C_   32
#define H_   256
#define W_   256
#define BC_  (B_ * C_)
#define HO_  (H_ - 2)           // 254
#define WO_  (W_ - 2)           // 254
#define NIN_  (BC_ * H_ * W_)   // 16,777,216
#define NBINS 256
#define HCOLS 16                // sub-histogram columns (LDS-atomic aliasing ~2-way = free)
#define HBLOCKS 1024            // NIN_/4 = HBLOCKS*256*16 exactly
#define TW4  65                 // pool tile row stride in int4 units (260 ints; cols 256..259 pad)

typedef float f2v __attribute__((ext_vector_type(2)));  // native vector: nontemporal-store OK

// Module-owned scratch (d_ws unsafe — R1). R4: deep global-atomic fan-in ~34 ns/op/addr
// — use plain-store partials + tree reduce. R7: fusion/grid.sync regressed (1 block/CU
// barrier serialization) — split kernels are the sync.
__device__ __align__(8) int g_hist[NBINS];
__device__ int g_part[HBLOCKS * NBINS];   // 1 MB partial histograms, plain stores

__global__ __launch_bounds__(256) void hist_kernel(const float* __restrict__ x) {
    __shared__ int sh[NBINS * HCOLS];   // 16 KB
    const int t = threadIdx.x;
    for (int i = t; i < NBINS * HCOLS; i += 256) sh[i] = 0;
    __syncthreads();

    const int col = t & (HCOLS - 1);
    const float4* x4 = (const float4*)x;
    const int stride = HBLOCKS * 256;          // 262144 float4s
    float4 v[8];
#pragma unroll
    for (int half = 0; half < 2; ++half) {
        const int base = blockIdx.x * 256 + t + half * 8 * stride;
#pragma unroll
        for (int k = 0; k < 8; ++k) v[k] = x4[base + k * stride];  // 8 loads in flight
#pragma unroll
        for (int k = 0; k < 8; ++k) {
            atomicAdd(&sh[((int)v[k].x) * HCOLS + col], 1);
            atomicAdd(&sh[((int)v[k].y) * HCOLS + col], 1);
            atomicAdd(&sh[((int)v[k].z) * HCOLS + col], 1);
            atomicAdd(&sh[((int)v[k].w) * HCOLS + col], 1);
        }
    }
    __syncthreads();

    // Per-bin column sum, rotated so bank alias is 2-way (free); plain store.
    int s0 = 0;
#pragma unroll
    for (int c = 0; c < HCOLS; ++c) s0 += sh[t * HCOLS + ((c + t) & (HCOLS - 1))];
    g_part[blockIdx.x * NBINS + t] = s0;
}

// Single 1024-thread block: tree-reduce 1024 partial rows with PLAIN stores.
__global__ __launch_bounds__(1024) void reduce_kernel() {
    __shared__ int acc[4 * NBINS];
    const int t = threadIdx.x;
    const int bin = t & (NBINS - 1);
    const int seg = t >> 8;                    // 0..3
    int s = 0;
#pragma unroll 16
    for (int r = seg * 256; r < seg * 256 + 256; ++r) s += g_part[r * NBINS + bin];
    acc[seg * NBINS + bin] = s;
    __syncthreads();
    if (t < NBINS) g_hist[t] = acc[t] + acc[NBINS + t] + acc[2 * NBINS + t] + acc[3 * NBINS + t];
}

// Pool v3: block = one (bc, 16-row strip); thread = 4 cols x 4 rows.
// Tile key = (count<<12)|value; per-tap cand = key | (pos<<8); v_min_i32 tree over 9
// cands == min over (count, pos, value) == EXACT first-position minimum (pos breaks
// count ties positionally; value bits can never decide since (count,pos) unique/window).
// count <= ~67k << 2^17 so count<<12 fits int32. Taps per row via two ds_read_b128
// (8 contiguous keys) instead of dependent b32 chains.
__global__ __launch_bounds__(256) void pool_kernel(const float* __restrict__ x,
                                                   float* __restrict__ out) {
    __shared__ int key_s[NBINS];
    __shared__ int4 tile[18 * TW4];   // 18,720 B (cols 256..259 pad, never used)
    const int t = threadIdx.x;
    key_s[t] = (g_hist[t] << 12) | t;
    __syncthreads();

    const int bc = blockIdx.x >> 4;
    const int s  = blockIdx.x & 15;
    const int r0 = s * 16;
    const int rows_out = (s == 15) ? 14 : 16;
    const int rows_in  = rows_out + 2;         // 18 / 16
    const int nf4 = rows_in * (W_ / 4);        // 1152 / 1024 (>= 1024 always)

    // Build: issue all global loads before any LDS op (MLP), then convert+store.
    const float4* xin = (const float4*)(x + ((long long)bc * H_ + r0) * W_);
    float4 v0 = xin[t], v1 = xin[t + 256], v2 = xin[t + 512], v3 = xin[t + 768];
    const bool tail = (t + 1024) < nf4;
    float4 v4;
    if (tail) v4 = xin[t + 1024];

#define PUT(i, v) { int4 k;                                                   \
        k.x = key_s[(int)(v).x]; k.y = key_s[(int)(v).y];                     \
        k.z = key_s[(int)(v).z]; k.w = key_s[(int)(v).w];                     \
        tile[((i) >> 6) * TW4 + ((i) & 63)] = k; }
    PUT(t, v0) PUT(t + 256, v1) PUT(t + 512, v2) PUT(t + 768, v3)
    if (tail) PUT(t + 1024, v4)
#undef PUT
    __syncthreads();

    // Compute: thread (tc,tr) -> output cols 4tc..4tc+3, rows o0..o0+rcnt-1.
    const int tc = t & 63;
    const int tr = t >> 6;
    const int o0 = tr * 4;
    const int rcnt = (rows_out - o0 < 4) ? (rows_out - o0) : 4;   // 4; strip15 tr3: 2
    const int4* tp = tile + tc;

    int4 a0 = tp[o0 * TW4],       a1 = tp[o0 * TW4 + 1];
    int4 b0 = tp[(o0 + 1) * TW4], b1 = tp[(o0 + 1) * TW4 + 1];
    float* obase = out + ((long long)bc * HO_ + r0 + o0) * WO_ + 4 * tc;

    for (int rr = 0; rr < rcnt; ++rr) {
        int4 c0 = tp[(o0 + 2 + rr) * TW4], c1 = tp[(o0 + 2 + rr) * TW4 + 1];
        const int A[6] = {a0.x, a0.y, a0.z, a0.w, a1.x, a1.y};
        const int Bt[6] = {b0.x, b0.y, b0.z, b0.w, b1.x, b1.y};
        const int Ct[6] = {c0.x, c0.y, c0.z, c0.w, c1.x, c1.y};
        float res[4];
#pragma unroll
        for (int c = 0; c < 4; ++c) {
            int m0 = min(min(A[c], A[c + 1] | 0x100), A[c + 2] | 0x200);
            int m1 = min(min(Bt[c] | 0x300, Bt[c + 1] | 0x400), Bt[c + 2] | 0x500);
            int m2 = min(min(Ct[c] | 0x600, Ct[c + 1] | 0x700), Ct[c + 2] | 0x800);
            res[c] = (float)(min(min(m0, m1), m2) & 255);
        }
        float* orow = obase + (long long)rr * WO_;
        f2v lo = { res[0], res[1] };
        __builtin_nontemporal_store(lo, (f2v*)orow);
        if (tc < 63) {  // cols 4tc+2,4tc+3 valid only below WO_=254
            f2v hi = { res[2], res[3] };
            __builtin_nontemporal_store(hi, (f2v*)(orow + 2));
        }
        a0 = b0; a1 = b1;
        b0 = c0; b1 = c1;
    }
}

extern "C" void kernel_launch(void* const* d_in, const int* in_sizes, int n_in,
                              void* d_out, int out_size, void* d_ws, size_t ws_size,
                              hipStream_t stream) {
    const float* x = (const float*)d_in[0];
    float* out = (float*)d_out;
    (void)d_ws; (void)ws_size;

    hist_kernel<<<HBLOCKS, 256, 0, stream>>>(x);
    reduce_kernel<<<1, 1024, 0, stream>>>();
    pool_kernel<<<BC_ * 16, 256, 0, stream>>>(x, out);
}

// Round 10
// 134.791 us; speedup vs baseline: 1.4005x; 1.1280x over previous
//
#include <hip/hip_runtime.h>

// x shape (8,32,256,256) float32 holding exact integers 0..255; K=3, stride 1, no pad.
#define B_   8
#define C_   32
#define H_   256
#define W_   256
#define BC_  (B_ * C_)
#define HO_  (H_ - 2)           // 254
#define WO_  (W_ - 2)           // 254
#define NIN_  (BC_ * H_ * W_)   // 16,777,216
#define NBINS 256
#define HCOLS 16                // sub-histogram columns (LDS-atomic aliasing ~2-way = free)
#define HBLOCKS 1024            // NIN_/4 = HBLOCKS*256*16 exactly
#define TW4  65                 // pool tile row stride in int4 units (260 ints; cols 256..259 pad)

typedef float f2v __attribute__((ext_vector_type(2)));

// Module-owned scratch (d_ws unsafe — R1). R4: deep global-atomic fan-in ~34 ns/op/addr
// — plain-store partials + tree reduce. R7: fusion/grid.sync regressed (1 block/CU
// barrier serialization). R9: nontemporal 8-B stores caused 1.8x HBM write
// amplification (evict-first flushes partial lines) — plain stores only.
__device__ __align__(8) int g_hist[NBINS];
__device__ int g_part[HBLOCKS * NBINS];   // 1 MB partial histograms, plain stores

__global__ __launch_bounds__(256) void hist_kernel(const float* __restrict__ x) {
    __shared__ int sh[NBINS * HCOLS];   // 16 KB
    const int t = threadIdx.x;
    for (int i = t; i < NBINS * HCOLS; i += 256) sh[i] = 0;
    __syncthreads();

    const int col = t & (HCOLS - 1);
    const float4* x4 = (const float4*)x;
    const int stride = HBLOCKS * 256;          // 262144 float4s
    float4 v[8];
#pragma unroll
    for (int half = 0; half < 2; ++half) {
        const int base = blockIdx.x * 256 + t + half * 8 * stride;
#pragma unroll
        for (int k = 0; k < 8; ++k) v[k] = x4[base + k * stride];  // 8 loads in flight
#pragma unroll
        for (int k = 0; k < 8; ++k) {
            atomicAdd(&sh[((int)v[k].x) * HCOLS + col], 1);
            atomicAdd(&sh[((int)v[k].y) * HCOLS + col], 1);
            atomicAdd(&sh[((int)v[k].z) * HCOLS + col], 1);
            atomicAdd(&sh[((int)v[k].w) * HCOLS + col], 1);
        }
    }
    __syncthreads();

    // Per-bin column sum, rotated so bank alias is 2-way (free); plain store.
    int s0 = 0;
#pragma unroll
    for (int c = 0; c < HCOLS; ++c) s0 += sh[t * HCOLS + ((c + t) & (HCOLS - 1))];
    g_part[blockIdx.x * NBINS + t] = s0;
}

// Single 1024-thread block: tree-reduce 1024 partial rows with PLAIN stores.
__global__ __launch_bounds__(1024) void reduce_kernel() {
    __shared__ int acc[4 * NBINS];
    const int t = threadIdx.x;
    const int bin = t & (NBINS - 1);
    const int seg = t >> 8;                    // 0..3
    int s = 0;
#pragma unroll 16
    for (int r = seg * 256; r < seg * 256 + 256; ++r) s += g_part[r * NBINS + bin];
    acc[seg * NBINS + bin] = s;
    __syncthreads();
    if (t < NBINS) g_hist[t] = acc[t] + acc[NBINS + t] + acc[2 * NBINS + t] + acc[3 * NBINS + t];
}

// Pool v4: block = one (bc, 16-row strip); thread = 4 cols x 4 rows.
// Tile key = (count<<12)|value; per-tap cand = key | (pos<<8); v_min_i32 tree over 9
// cands == min over (count, pos, value) == EXACT first-position minimum (pos breaks
// count ties positionally; value bits can never decide since (count,pos) unique/window).
// count <= ~67k << 2^17 so count<<12 fits int32. Taps per row via two ds_read_b128.
// Output: plain 8-B float2 stores (always 8-aligned; lane-contiguous = coalesced).
__global__ __launch_bounds__(256) void pool_kernel(const float* __restrict__ x,
                                                   float* __restrict__ out) {
    __shared__ int key_s[NBINS];
    __shared__ int4 tile[18 * TW4];   // 18,720 B (cols 256..259 pad, never used)
    const int t = threadIdx.x;
    key_s[t] = (g_hist[t] << 12) | t;
    __syncthreads();

    const int bc = blockIdx.x >> 4;
    const int s  = blockIdx.x & 15;
    const int r0 = s * 16;
    const int rows_out = (s == 15) ? 14 : 16;
    const int rows_in  = rows_out + 2;         // 18 / 16
    const int nf4 = rows_in * (W_ / 4);        // 1152 / 1024 (>= 1024 always)

    // Build: issue all global loads before any LDS op (MLP), then convert+store.
    const float4* xin = (const float4*)(x + ((long long)bc * H_ + r0) * W_);
    float4 v0 = xin[t], v1 = xin[t + 256], v2 = xin[t + 512], v3 = xin[t + 768];
    const bool tail = (t + 1024) < nf4;
    float4 v4;
    if (tail) v4 = xin[t + 1024];

#define PUT(i, v) { int4 k;                                                   \
        k.x = key_s[(int)(v).x]; k.y = key_s[(int)(v).y];                     \
        k.z = key_s[(int)(v).z]; k.w = key_s[(int)(v).w];                     \
        tile[((i) >> 6) * TW4 + ((i) & 63)] = k; }
    PUT(t, v0) PUT(t + 256, v1) PUT(t + 512, v2) PUT(t + 768, v3)
    if (tail) PUT(t + 1024, v4)
#undef PUT
    __syncthreads();

    // Compute: thread (tc,tr) -> output cols 4tc..4tc+3, rows o0..o0+rcnt-1.
    const int tc = t & 63;
    const int tr = t >> 6;
    const int o0 = tr * 4;
    const int rcnt = (rows_out - o0 < 4) ? (rows_out - o0) : 4;   // 4; strip15 tr3: 2
    const int4* tp = tile + tc;

    int4 a0 = tp[o0 * TW4],       a1 = tp[o0 * TW4 + 1];
    int4 b0 = tp[(o0 + 1) * TW4], b1 = tp[(o0 + 1) * TW4 + 1];
    float* obase = out + ((long long)bc * HO_ + r0 + o0) * WO_ + 4 * tc;

    for (int rr = 0; rr < rcnt; ++rr) {
        int4 c0 = tp[(o0 + 2 + rr) * TW4], c1 = tp[(o0 + 2 + rr) * TW4 + 1];
        const int A[6] = {a0.x, a0.y, a0.z, a0.w, a1.x, a1.y};
        const int Bt[6] = {b0.x, b0.y, b0.z, b0.w, b1.x, b1.y};
        const int Ct[6] = {c0.x, c0.y, c0.z, c0.w, c1.x, c1.y};
        float res[4];
#pragma unroll
        for (int c = 0; c < 4; ++c) {
            int m0 = min(min(A[c], A[c + 1] | 0x100), A[c + 2] | 0x200);
            int m1 = min(min(Bt[c] | 0x300, Bt[c + 1] | 0x400), Bt[c + 2] | 0x500);
            int m2 = min(min(Ct[c] | 0x600, Ct[c + 1] | 0x700), Ct[c + 2] | 0x800);
            res[c] = (float)(min(min(m0, m1), m2) & 255);
        }
        float* orow = obase + (long long)rr * WO_;
        *(f2v*)orow = (f2v){ res[0], res[1] };
        if (tc < 63)   // cols 4tc+2,4tc+3 valid only below WO_=254
            *(f2v*)(orow + 2) = (f2v){ res[2], res[3] };
        a0 = b0; a1 = b1;
        b0 = c0; b1 = c1;
    }
}

extern "C" void kernel_launch(void* const* d_in, const int* in_sizes, int n_in,
                              void* d_out, int out_size, void* d_ws, size_t ws_size,
                              hipStream_t stream) {
    const float* x = (const float*)d_in[0];
    float* out = (float*)d_out;
    (void)d_ws; (void)ws_size;

    hist_kernel<<<HBLOCKS, 256, 0, stream>>>(x);
    reduce_kernel<<<1, 1024, 0, stream>>>();
    pool_kernel<<<BC_ * 16, 256, 0, stream>>>(x, out);
}